// Round 6
// baseline (87.104 us; speedup 1.0000x reference)
//
#include <hip/hip_runtime.h>
#include <hip/hip_bf16.h>
#include <cstdint>

#define HDIM 2048
#define INDIM 4096
#define CDIM 4096
#define KDIM 2048   // GEMM K = hidden size

typedef __attribute__((ext_vector_type(4))) int int4v;

__device__ __forceinline__ void gload16(const void* g, void* l) {
  __builtin_amdgcn_global_load_lds(
      (const __attribute__((address_space(1))) void*)g,
      (__attribute__((address_space(3))) void*)l, 16, 0, 0);
}

// ---------------- Kernel 1: i8 row-quant (c_input, aW_hh) + xa2 GEMV ----------
// blocks [0,1536):    quant rows, wave w -> row blockIdx*4+w  (6144 rows)
// blocks [1536,2048): xa2[h] = x @ aW_ih[h] + ab_ih[h] + ab_hh[h]
__global__ __launch_bounds__(256) void k_quant_xa2(
    const float* __restrict__ c_input, const float* __restrict__ aW_hh,
    int8_t* __restrict__ a8, int8_t* __restrict__ b8,
    float* __restrict__ dAs, float* __restrict__ dBs,
    const float* __restrict__ x,
    const float* __restrict__ aW_ih, const float* __restrict__ ab_ih,
    const float* __restrict__ ab_hh,
    float* __restrict__ xa2, float* __restrict__ accz) {
  const int t = threadIdx.x;
  const int wid = t >> 6, lane = t & 63;

  if (blockIdx.x < 1536) {
    if (blockIdx.x == 0) {  // zero acc_se/acc_sce (4096 floats) every launch
#pragma unroll
      for (int i = 0; i < 16; ++i) accz[i * 256 + t] = 0.f;
    }
    const int row = blockIdx.x * 4 + wid;
    const float* src; int8_t* dst; float* dsc; int r;
    if (row < CDIM) { src = c_input; dst = a8; dsc = dAs; r = row; }
    else            { src = aW_hh;  dst = b8; dsc = dBs; r = row - CDIM; }
    const float4* s4 = (const float4*)(src + (size_t)r * KDIM);
    float4 v[8];
#pragma unroll
    for (int it = 0; it < 8; ++it) v[it] = s4[it * 64 + lane];
    float am = 0.f;
#pragma unroll
    for (int it = 0; it < 8; ++it)
      am = fmaxf(am, fmaxf(fmaxf(fabsf(v[it].x), fabsf(v[it].y)),
                           fmaxf(fabsf(v[it].z), fabsf(v[it].w))));
#pragma unroll
    for (int off = 32; off > 0; off >>= 1) am = fmaxf(am, __shfl_xor(am, off));
    am = fmaxf(am, 1e-20f);
    const float inv = 127.0f / am;
    uint32_t* qd = (uint32_t*)(dst + (size_t)r * KDIM);
#pragma unroll
    for (int it = 0; it < 8; ++it) {
      uint32_t p = (uint32_t)(__float2int_rn(v[it].x * inv) & 0xFF)
                 | ((uint32_t)(__float2int_rn(v[it].y * inv) & 0xFF) << 8)
                 | ((uint32_t)(__float2int_rn(v[it].z * inv) & 0xFF) << 16)
                 | ((uint32_t)(__float2int_rn(v[it].w * inv) & 0xFF) << 24);
      qd[it * 64 + lane] = p;
    }
    if (lane == 0) dsc[r] = am * (1.0f / 127.0f);
    return;
  }

  // ---- xa2 GEMV: one wave per h ----
  const int h = (blockIdx.x - 1536) * 4 + wid;
  const float4* x4 = (const float4*)x;
  const float4* wr4 = (const float4*)(aW_ih + (size_t)h * INDIM);
  float sum = 0.f;
#pragma unroll
  for (int g = 0; g < 2; ++g) {
    float4 w[8];
#pragma unroll
    for (int it = 0; it < 8; ++it) w[it] = wr4[(g * 8 + it) * 64 + lane];
#pragma unroll
    for (int it = 0; it < 8; ++it) {
      float4 xv = x4[(g * 8 + it) * 64 + lane];
      sum += w[it].x * xv.x + w[it].y * xv.y + w[it].z * xv.z + w[it].w * xv.w;
    }
  }
#pragma unroll
  for (int off = 32; off > 0; off >>= 1) sum += __shfl_down(sum, off);
  if (lane == 0) xa2[h] = sum + ab_ih[h] + ab_hh[h];
}

// ---------------- Kernel 2: wave-specialized fat kernel -----------------------
// 512 blocks x 512 threads. Waves 0-3: barrier-free per-wave i8 MFMA GEMM
// (64x64 output quadrant each, private double-buffered LDS, counted vmcnt(8)
// pipeline — no __syncthreads anywhere, so waves 4-7 stream the gate GEMVs
// completely independently). Every CU holds 8 GEMM + 8 GEMV waves (2 blocks/CU
// by 64 KB LDS) -> structural compute/BW overlap (m114).
// GEMM: alpha_pre[j][h] = dA[j]*dB[h] * sum_k qa[j][k]*qb[h][k], i32 exact;
// fused sigmoid/exp/column-reduce epilogue with atomics.
// LDS: 64-B rows, swizzle byte ^= (row&3)<<4 on pre-swizzled global source
// (rule #21) and on ds_read -> 4-way residual (acceptable, 1.58x per m136).
__global__ __launch_bounds__(512, 4) void k_fat(
    const int8_t* __restrict__ A, const int8_t* __restrict__ B,
    const float* __restrict__ dAs, const float* __restrict__ dBs,
    const float* __restrict__ c_in, const float* __restrict__ xa2,
    float* __restrict__ acc_se, float* __restrict__ acc_sce,
    const float* __restrict__ x, const float* __restrict__ h0,
    const float* __restrict__ W_ih, const float* __restrict__ b_ih,
    const float* __restrict__ W_hh, const float* __restrict__ b_hh,
    float* __restrict__ i_sig, float* __restrict__ o_sig,
    float* __restrict__ g_tanh) {
  __shared__ uint8_t lds[4][2][2][4096];  // [gemm-wave][buf][A|B][4 KB]
  const int t = threadIdx.x;
  const int wid = t >> 6, lane = t & 63;

  if (wid < 4) {
    // ================= GEMM wave: 64x64 quadrant =================
    const int wr = wid >> 1, wc = wid & 1;
    const int l15 = lane & 15, l4 = lane >> 4;
    const int bm = blockIdx.x & 31, bn = blockIdx.x >> 5;  // 32 x 16 tiles
    const int arow0 = bm * 128 + wr * 64;
    const int brow0 = bn * 128 + wc * 64;
    uint8_t* wbase = &lds[wid][0][0][0];

    // staging geometry: per gload16 q: LDS row = q*16 + lane/4, colb = (lane&3)*16
    const int srow = lane >> 2;
    const int scolb = ((lane & 3) * 16) ^ ((srow & 3) << 4);  // pre-swizzled src
    const int8_t* Asrc = A + (size_t)(arow0 + srow) * KDIM + scolb;
    const int8_t* Bsrc = B + (size_t)(brow0 + srow) * KDIM + scolb;

    int4v acc[4][4] = {};

#define STG(buf, kt)                                                           \
    do {                                                                       \
      _Pragma("unroll")                                                        \
      for (int q = 0; q < 4; ++q) {                                            \
        gload16(Asrc + (size_t)q * 16 * KDIM + (size_t)(kt) * 64,              \
                wbase + (buf) * 8192 + q * 1024 + lane * 16);                  \
        gload16(Bsrc + (size_t)q * 16 * KDIM + (size_t)(kt) * 64,              \
                wbase + (buf) * 8192 + 4096 + q * 1024 + lane * 16);           \
      }                                                                        \
    } while (0)

    STG(0, 0);
    STG(1, 1);  // 16 loads outstanding

    for (int ti = 0; ti < KDIM / 64; ++ti) {  // 32 k-tiles
      const int cur = ti & 1;
      if (ti < KDIM / 64 - 1) {
        asm volatile("s_waitcnt vmcnt(8)" ::: "memory");  // buf[cur] landed
      } else {
        asm volatile("s_waitcnt vmcnt(0)" ::: "memory");  // last tile: drain
      }
      const uint8_t* Ab = wbase + cur * 8192;
      const uint8_t* Bb = Ab + 4096;
      int4v bf[4];
#pragma unroll
      for (int n = 0; n < 4; ++n) {
        const int r = n * 16 + l15;
        bf[n] = *(const int4v*)(Bb + r * 64 + ((l4 * 16) ^ ((r & 3) << 4)));
      }
#pragma unroll
      for (int m = 0; m < 4; ++m) {
        const int r = m * 16 + l15;
        int4v af = *(const int4v*)(Ab + r * 64 + ((l4 * 16) ^ ((r & 3) << 4)));
#pragma unroll
        for (int n = 0; n < 4; ++n)
          acc[m][n] = __builtin_amdgcn_mfma_i32_16x16x64_i8(af, bf[n], acc[m][n], 0, 0, 0);
      }
      if (ti < KDIM / 64 - 2) {
        // LDS reads of buf[cur] must complete before DMA overwrites it
        asm volatile("s_waitcnt lgkmcnt(0)" ::: "memory");
        STG(cur, ti + 2);
      }
    }
#undef STG

    // epilogue: D layout col = lane&15, row = (lane>>4)*4 + reg [m89-verified]
#pragma unroll
    for (int n = 0; n < 4; ++n) {
      const int hcol = brow0 + n * 16 + l15;
      const float xa = xa2[hcol];
      const float db = dBs[hcol];
      float se = 0.f, sce = 0.f;
#pragma unroll
      for (int m = 0; m < 4; ++m) {
        const int jbase = arow0 + m * 16 + l4 * 4;
#pragma unroll
        for (int rr = 0; rr < 4; ++rr) {
          const float sc = dAs[jbase + rr] * db;
          float z = (float)acc[m][n][rr] * sc + xa;
          float s = 1.f / (1.f + __expf(-z));
          float e = __expf(s);
          se += e;
          sce += c_in[(size_t)(jbase + rr) * HDIM + hcol] * e;
        }
      }
      se += __shfl_xor(se, 16); se += __shfl_xor(se, 32);
      sce += __shfl_xor(sce, 16); sce += __shfl_xor(sce, 32);
      if (l4 == 0) {
        atomicAdd(&acc_se[hcol], se);
        atomicAdd(&acc_sce[hcol], sce);
      }
    }
    return;
  }

  // ================= GEMV wave: gates i,o,g for h = g ==================
  const int g = blockIdx.x * 4 + (wid - 4);  // [0, 2048)
  const float4* x4 = (const float4*)x;
  const float4* h4 = (const float4*)h0;
#pragma unroll
  for (int typ = 0; typ < 3; ++typ) {
    const int grow = (typ == 0) ? g : (typ == 1) ? (2 * HDIM + g) : (3 * HDIM + g);
    float sum = 0.f;
    const float4* wr4 = (const float4*)(W_ih + (size_t)grow * INDIM);
#pragma unroll
    for (int gg = 0; gg < 2; ++gg) {  // 2 batches of 8 loads in flight
      float4 w[8];
#pragma unroll
      for (int it = 0; it < 8; ++it) w[it] = wr4[(gg * 8 + it) * 64 + lane];
#pragma unroll
      for (int it = 0; it < 8; ++it) {
        float4 xv = x4[(gg * 8 + it) * 64 + lane];
        sum += w[it].x * xv.x + w[it].y * xv.y + w[it].z * xv.z + w[it].w * xv.w;
      }
    }
    {
      const float4* wh4 = (const float4*)(W_hh + (size_t)grow * HDIM);
      float4 w[8];
#pragma unroll
      for (int it = 0; it < 8; ++it) w[it] = wh4[it * 64 + lane];
#pragma unroll
      for (int it = 0; it < 8; ++it) {
        float4 hv = h4[it * 64 + lane];
        sum += w[it].x * hv.x + w[it].y * hv.y + w[it].z * hv.z + w[it].w * hv.w;
      }
    }
#pragma unroll
    for (int off = 32; off > 0; off >>= 1) sum += __shfl_down(sum, off);
    if (lane == 0) {
      float z = sum + b_ih[grow] + b_hh[grow];
      if (typ == 0)      i_sig[g] = 1.f / (1.f + expf(-z));
      else if (typ == 1) o_sig[g] = 1.f / (1.f + expf(-z));
      else               g_tanh[g] = tanhf(z);
    }
  }
}

// ---------------- Kernel 3: finalize ------------------------------------------
__global__ __launch_bounds__(256) void k_final(
    const float* __restrict__ i_sig, const float* __restrict__ o_sig,
    const float* __restrict__ g_tanh, const float* __restrict__ acc_se,
    const float* __restrict__ acc_sce, float* __restrict__ out) {
  int h = blockIdx.x * 256 + threadIdx.x;
  if (h >= HDIM) return;
  float wi = expf(i_sig[h]);
  float tot = acc_se[h] + wi;
  float c1 = (acc_sce[h] + g_tanh[h] * wi) / tot;
  float h1 = o_sig[h] * tanhf(c1);
  out[h] = h1;
  out[HDIM + h] = c1;
}

extern "C" void kernel_launch(void* const* d_in, const int* in_sizes, int n_in,
                              void* d_out, int out_size, void* d_ws, size_t ws_size,
                              hipStream_t stream) {
  const float* x     = (const float*)d_in[0];
  const float* c_inp = (const float*)d_in[1];
  const float* h0    = (const float*)d_in[2];
  // d_in[3] = c0: unused by the reference output
  const float* W_ih  = (const float*)d_in[4];
  const float* b_ih  = (const float*)d_in[5];
  const float* W_hh  = (const float*)d_in[6];
  const float* b_hh  = (const float*)d_in[7];
  const float* aW_ih = (const float*)d_in[8];
  const float* ab_ih = (const float*)d_in[9];
  const float* aW_hh = (const float*)d_in[10];
  const float* ab_hh = (const float*)d_in[11];
  float* out = (float*)d_out;

  char* ws = (char*)d_ws;
  int8_t* a8 = (int8_t*)ws;                          // 8 MB i8 c_input
  int8_t* b8 = a8 + (size_t)CDIM * KDIM;             // 4 MB i8 aW_hh
  float* dAs = (float*)(b8 + (size_t)HDIM * KDIM);   // 16 KB row scales A
  float* dBs = dAs + CDIM;                           // 8 KB row scales B
  float* fb  = dBs + HDIM;
  float* i_sig   = fb;
  float* o_sig   = fb + HDIM;
  float* g_tanh  = fb + 2 * HDIM;
  float* xa2     = fb + 3 * HDIM;
  float* acc_se  = fb + 4 * HDIM;   // acc_se/acc_sce contiguous: zeroed together
  float* acc_sce = fb + 5 * HDIM;

  // k1: 1536 quant blocks (6144 rows) + 512 xa2-GEMV blocks
  k_quant_xa2<<<2048, 256, 0, stream>>>(
      c_inp, aW_hh, a8, b8, dAs, dBs, x, aW_ih, ab_ih, ab_hh, xa2, acc_se);
  // k2: 512 blocks x 512 threads; waves 0-3 GEMM, waves 4-7 gate GEMVs
  k_fat<<<512, 512, 0, stream>>>(
      a8, b8, dAs, dBs, c_inp, xa2, acc_se, acc_sce,
      x, h0, W_ih, b_ih, W_hh, b_hh, i_sig, o_sig, g_tanh);
  k_final<<<(HDIM + 255) / 256, 256, 0, stream>>>(i_sig, o_sig, g_tanh,
                                                  acc_se, acc_sce, out);
}

// Round 7
// 66.516 us; speedup vs baseline: 1.3095x; 1.3095x over previous
//
#include <hip/hip_runtime.h>
#include <hip/hip_bf16.h>
#include <cstdint>

#define HDIM 2048
#define INDIM 4096
#define CDIM 4096
#define KDIM 2048   // GEMM K = hidden size

typedef __attribute__((ext_vector_type(4))) int int4v;

__device__ __forceinline__ void gload16(const void* g, void* l) {
  __builtin_amdgcn_global_load_lds(
      (const __attribute__((address_space(1))) void*)g,
      (__attribute__((address_space(3))) void*)l, 16, 0, 0);
}

// ---------------- Kernel 1: i8 row-quant (c_input, aW_hh) + xa2 GEMV ----------
// blocks [0,1536):    quant rows, wave w -> row blockIdx*4+w  (6144 rows)
// blocks [1536,2048): xa2[h] = x @ aW_ih[h] + ab_ih[h] + ab_hh[h]
__global__ __launch_bounds__(256) void k_quant_xa2(
    const float* __restrict__ c_input, const float* __restrict__ aW_hh,
    int8_t* __restrict__ a8, int8_t* __restrict__ b8,
    float* __restrict__ dAs, float* __restrict__ dBs,
    const float* __restrict__ x,
    const float* __restrict__ aW_ih, const float* __restrict__ ab_ih,
    const float* __restrict__ ab_hh,
    float* __restrict__ xa2, float* __restrict__ accz) {
  const int t = threadIdx.x;
  const int wid = t >> 6, lane = t & 63;

  if (blockIdx.x < 1536) {
    if (blockIdx.x == 0) {  // zero acc_se/acc_sce (4096 floats) every launch
#pragma unroll
      for (int i = 0; i < 16; ++i) accz[i * 256 + t] = 0.f;
    }
    const int row = blockIdx.x * 4 + wid;
    const float* src; int8_t* dst; float* dsc; int r;
    if (row < CDIM) { src = c_input; dst = a8; dsc = dAs; r = row; }
    else            { src = aW_hh;  dst = b8; dsc = dBs; r = row - CDIM; }
    const float4* s4 = (const float4*)(src + (size_t)r * KDIM);
    float4 v[8];
#pragma unroll
    for (int it = 0; it < 8; ++it) v[it] = s4[it * 64 + lane];
    float am = 0.f;
#pragma unroll
    for (int it = 0; it < 8; ++it)
      am = fmaxf(am, fmaxf(fmaxf(fabsf(v[it].x), fabsf(v[it].y)),
                           fmaxf(fabsf(v[it].z), fabsf(v[it].w))));
#pragma unroll
    for (int off = 32; off > 0; off >>= 1) am = fmaxf(am, __shfl_xor(am, off));
    am = fmaxf(am, 1e-20f);
    const float inv = 127.0f / am;
    uint32_t* qd = (uint32_t*)(dst + (size_t)r * KDIM);
#pragma unroll
    for (int it = 0; it < 8; ++it) {
      uint32_t p = (uint32_t)(__float2int_rn(v[it].x * inv) & 0xFF)
                 | ((uint32_t)(__float2int_rn(v[it].y * inv) & 0xFF) << 8)
                 | ((uint32_t)(__float2int_rn(v[it].z * inv) & 0xFF) << 16)
                 | ((uint32_t)(__float2int_rn(v[it].w * inv) & 0xFF) << 24);
      qd[it * 64 + lane] = p;
    }
    if (lane == 0) dsc[r] = am * (1.0f / 127.0f);
    return;
  }

  // ---- xa2 GEMV: one wave per h ----
  const int h = (blockIdx.x - 1536) * 4 + wid;
  const float4* x4 = (const float4*)x;
  const float4* wr4 = (const float4*)(aW_ih + (size_t)h * INDIM);
  float sum = 0.f;
#pragma unroll
  for (int g = 0; g < 2; ++g) {
    float4 w[8];
#pragma unroll
    for (int it = 0; it < 8; ++it) w[it] = wr4[(g * 8 + it) * 64 + lane];
#pragma unroll
    for (int it = 0; it < 8; ++it) {
      float4 xv = x4[(g * 8 + it) * 64 + lane];
      sum += w[it].x * xv.x + w[it].y * xv.y + w[it].z * xv.z + w[it].w * xv.w;
    }
  }
#pragma unroll
  for (int off = 32; off > 0; off >>= 1) sum += __shfl_down(sum, off);
  if (lane == 0) xa2[h] = sum + ab_ih[h] + ab_hh[h];
}

// ---------------- Kernel 2: fat kernel = i8 GEMM  ||  gate GEMVs --------------
// blocks [0,512):    GEMM 128x128 tile, BK=64 double-buffered (32 KB LDS),
//                    mfma_i32_16x16x64_i8, i32 exact accum, fused
//                    sigmoid/exp/column-reduce epilogue with atomics.
//                    Tile map: bn = (bid&7)*2 + ((bid>>3)&1), bm = bid>>4 —
//                    each XCD (bid%8 round-robin) owns 2 bn-panels (512 KB
//                    B L2-resident), A panels stream from L3.
// blocks [512,2048): gate GEMVs (i,o,g): HBM streaming overlaps GEMM compute.
// LDS swizzle (CORRECTED, r6 post-mortem): p(r) = ((r>>1)&3)<<4. For a b128
// 16-lane phase, granule = (4r + p(r)) mod 8 covers every residue exactly 2x
// -> 2-way = free (m136). Old (r&3) variant was 4-way (1.58x) on the GEMM's
// LDS-read critical path. Applied on pre-swizzled global source (rule #21,
// linear gload_lds dest) and on ds_read.
__global__ __launch_bounds__(256, 4) void k_gemm_gemv(
    const int8_t* __restrict__ A, const int8_t* __restrict__ B,
    const float* __restrict__ dAs, const float* __restrict__ dBs,
    const float* __restrict__ c_in, const float* __restrict__ xa2,
    float* __restrict__ acc_se, float* __restrict__ acc_sce,
    const float* __restrict__ x, const float* __restrict__ h0,
    const float* __restrict__ W_ih, const float* __restrict__ b_ih,
    const float* __restrict__ W_hh, const float* __restrict__ b_hh,
    float* __restrict__ i_sig, float* __restrict__ o_sig,
    float* __restrict__ g_tanh) {
  __shared__ uint8_t As[2][8192];  // 128 rows x 64 k-bytes, double-buffered
  __shared__ uint8_t Bs[2][8192];
  const int t = threadIdx.x;
  const int lane = t & 63, wid = t >> 6;

  if (blockIdx.x < 512) {
    // ================= GEMM path =================
    const int wr = wid >> 1, wc = wid & 1;
    const int l15 = lane & 15, l4 = lane >> 4;
    const int bid = blockIdx.x;
    const int bn = (bid & 7) * 2 + ((bid >> 3) & 1);  // XCD-grouped B panels
    const int bm = bid >> 4;
    const int m0 = bm * 128, n0 = bn * 128;

    int4v acc[4][4] = {};

    // staging: per matrix 8 KB/step = 2 x 16B per thread.
    // phys chunk (row r = q*64 + t>>2, j = t&3) holds global chunk j ^ p(r);
    // p(r) = (r>>1)&3  (q*64 doesn't change p: 32q = 0 mod 4)
    const int trow = t >> 2;
    const int tcol = (((t & 3) ^ ((trow >> 1) & 3)) * 16);  // pre-swizzled src
    const int8_t* Arow = A + (size_t)(m0 + trow) * KDIM + tcol;
    const int8_t* Brow = B + (size_t)(n0 + trow) * KDIM + tcol;

#define STAGE(buf, k0)                                                          \
    do {                                                                        \
      _Pragma("unroll")                                                         \
      for (int qq = 0; qq < 2; ++qq) {                                          \
        gload16(Arow + (size_t)qq * 64 * KDIM + (k0), As[buf] + qq * 4096 + t * 16); \
        gload16(Brow + (size_t)qq * 64 * KDIM + (k0), Bs[buf] + qq * 4096 + t * 16); \
      }                                                                         \
    } while (0)

    STAGE(0, 0);
    __syncthreads();  // implicit vmcnt(0) drain -> buf0 ready

    int cur = 0;
    for (int ti = 0; ti < KDIM / 64; ++ti) {  // 32 iterations
      if (ti < KDIM / 64 - 1) STAGE(cur ^ 1, (ti + 1) * 64);
      int4v af[4], bfr[4];
#pragma unroll
      for (int m = 0; m < 4; ++m) {
        const int r = wr * 64 + m * 16 + l15;
        af[m] = *(const int4v*)(As[cur] + r * 64 + ((l4 ^ ((r >> 1) & 3)) * 16));
      }
#pragma unroll
      for (int n = 0; n < 4; ++n) {
        const int r = wc * 64 + n * 16 + l15;
        bfr[n] = *(const int4v*)(Bs[cur] + r * 64 + ((l4 ^ ((r >> 1) & 3)) * 16));
      }
#pragma unroll
      for (int m = 0; m < 4; ++m)
#pragma unroll
        for (int n = 0; n < 4; ++n)
          acc[m][n] = __builtin_amdgcn_mfma_i32_16x16x64_i8(af[m], bfr[n], acc[m][n], 0, 0, 0);
      __syncthreads();  // reads of cur done; staging into cur^1 drained
      cur ^= 1;
    }
#undef STAGE

    // epilogue: D layout col = lane&15, row = (lane>>4)*4 + reg [m89-verified]
#pragma unroll
    for (int n = 0; n < 4; ++n) {
      const int hcol = n0 + wc * 64 + n * 16 + l15;
      const float xa = xa2[hcol];
      const float db = dBs[hcol];
      float se = 0.f, sce = 0.f;
#pragma unroll
      for (int m = 0; m < 4; ++m) {
        const int jbase = m0 + wr * 64 + m * 16 + l4 * 4;
#pragma unroll
        for (int rr = 0; rr < 4; ++rr) {
          const float sc = dAs[jbase + rr] * db;
          float z = (float)acc[m][n][rr] * sc + xa;
          float s = 1.f / (1.f + __expf(-z));
          float e = __expf(s);
          se += e;
          sce += c_in[(size_t)(jbase + rr) * HDIM + hcol] * e;
        }
      }
      se += __shfl_xor(se, 16); se += __shfl_xor(se, 32);
      sce += __shfl_xor(sce, 16); sce += __shfl_xor(sce, 32);
      if (l4 == 0) {
        atomicAdd(&acc_se[hcol], se);
        atomicAdd(&acc_sce[hcol], sce);
      }
    }
    return;
  }

  // ================= gate GEMV path (i, o, g) =================
  const int vr = (blockIdx.x - 512) * 4 + wid;  // [0, 6144)
  const int typ = vr >> 11;                     // 0=i, 1=o, 2=g
  const int h = vr & (HDIM - 1);
  const int grow = (typ == 0) ? h : (typ == 1) ? (2 * HDIM + h) : (3 * HDIM + h);
  float sum = 0.f;
  const float4* x4 = (const float4*)x;
  const float4* wr4 = (const float4*)(W_ih + (size_t)grow * INDIM);
#pragma unroll
  for (int g = 0; g < 2; ++g) {  // 2 batches of 8 loads
    float4 w[8];
#pragma unroll
    for (int it = 0; it < 8; ++it) w[it] = wr4[(g * 8 + it) * 64 + lane];
#pragma unroll
    for (int it = 0; it < 8; ++it) {
      float4 xv = x4[(g * 8 + it) * 64 + lane];
      sum += w[it].x * xv.x + w[it].y * xv.y + w[it].z * xv.z + w[it].w * xv.w;
    }
  }
  {
    const float4* wh4 = (const float4*)(W_hh + (size_t)grow * HDIM);
    const float4* h4 = (const float4*)h0;
    float4 w[8];
#pragma unroll
    for (int it = 0; it < 8; ++it) w[it] = wh4[it * 64 + lane];
#pragma unroll
    for (int it = 0; it < 8; ++it) {
      float4 hv = h4[it * 64 + lane];
      sum += w[it].x * hv.x + w[it].y * hv.y + w[it].z * hv.z + w[it].w * hv.w;
    }
  }
#pragma unroll
  for (int off = 32; off > 0; off >>= 1) sum += __shfl_down(sum, off);
  if (lane == 0) {
    float z = sum + b_ih[grow] + b_hh[grow];
    if (typ == 0)      i_sig[h] = 1.f / (1.f + expf(-z));
    else if (typ == 1) o_sig[h] = 1.f / (1.f + expf(-z));
    else               g_tanh[h] = tanhf(z);
  }
}

// ---------------- Kernel 3: finalize ------------------------------------------
__global__ __launch_bounds__(256) void k_final(
    const float* __restrict__ i_sig, const float* __restrict__ o_sig,
    const float* __restrict__ g_tanh, const float* __restrict__ acc_se,
    const float* __restrict__ acc_sce, float* __restrict__ out) {
  int h = blockIdx.x * 256 + threadIdx.x;
  if (h >= HDIM) return;
  float wi = expf(i_sig[h]);
  float tot = acc_se[h] + wi;
  float c1 = (acc_sce[h] + g_tanh[h] * wi) / tot;
  float h1 = o_sig[h] * tanhf(c1);
  out[h] = h1;
  out[HDIM + h] = c1;
}

extern "C" void kernel_launch(void* const* d_in, const int* in_sizes, int n_in,
                              void* d_out, int out_size, void* d_ws, size_t ws_size,
                              hipStream_t stream) {
  const float* x     = (const float*)d_in[0];
  const float* c_inp = (const float*)d_in[1];
  const float* h0    = (const float*)d_in[2];
  // d_in[3] = c0: unused by the reference output
  const float* W_ih  = (const float*)d_in[4];
  const float* b_ih  = (const float*)d_in[5];
  const float* W_hh  = (const float*)d_in[6];
  const float* b_hh  = (const float*)d_in[7];
  const float* aW_ih = (const float*)d_in[8];
  const float* ab_ih = (const float*)d_in[9];
  const float* aW_hh = (const float*)d_in[10];
  const float* ab_hh = (const float*)d_in[11];
  float* out = (float*)d_out;

  char* ws = (char*)d_ws;
  int8_t* a8 = (int8_t*)ws;                          // 8 MB i8 c_input
  int8_t* b8 = a8 + (size_t)CDIM * KDIM;             // 4 MB i8 aW_hh
  float* dAs = (float*)(b8 + (size_t)HDIM * KDIM);   // 16 KB row scales A
  float* dBs = dAs + CDIM;                           // 8 KB row scales B
  float* fb  = dBs + HDIM;
  float* i_sig   = fb;
  float* o_sig   = fb + HDIM;
  float* g_tanh  = fb + 2 * HDIM;
  float* xa2     = fb + 3 * HDIM;
  float* acc_se  = fb + 4 * HDIM;   // acc_se/acc_sce contiguous: zeroed together
  float* acc_sce = fb + 5 * HDIM;

  // k1: 1536 quant blocks (6144 rows) + 512 xa2-GEMV blocks
  k_quant_xa2<<<2048, 256, 0, stream>>>(
      c_inp, aW_hh, a8, b8, dAs, dBs, x, aW_ih, ab_ih, ab_hh, xa2, acc_se);
  // k2: 512 GEMM blocks (first -> co-resident with backfilling GEMV blocks)
  k_gemm_gemv<<<512 + 1536, 256, 0, stream>>>(
      a8, b8, dAs, dBs, c_inp, xa2, acc_se, acc_sce,
      x, h0, W_ih, b_ih, W_hh, b_hh, i_sig, o_sig, g_tanh);
  k_final<<<(HDIM + 255) / 256, 256, 0, stream>>>(i_sig, o_sig, g_tanh,
                                                  acc_se, acc_sce, out);
}